// Round 9
// baseline (182.389 us; speedup 1.0000x reference)
//
#include <hip/hip_runtime.h>
#include <hip/hip_bf16.h>
#include <cstdint>
#include <cstddef>

// Problem constants
#define Hh    12
#define Nseq  2048
#define PSTR  1152      // concat projection width: 192 q | 384 kv | 144 qp | 432 kvp
#define EPSm  1e-8f
#define MASKV 1024.0f   // (mi*M)*mj + (-M)*1 == 0 exactly when masks==1

typedef unsigned short ushort_t;
typedef __attribute__((ext_vector_type(8))) short bf8_t;   // 8 bf16 (4 VGPRs)
typedef __attribute__((ext_vector_type(4))) short s4_t;    // 4 bf16 (2 VGPRs)
typedef __attribute__((ext_vector_type(4))) float f4_t;    // MFMA C/D

// ws offsets (floats). Total 4,030,464 fl = 16.1 MB <= proven 29.1 MB budget.
#define OFF_PALL   0         // fp32 [2048][1152]
#define OFF_FEATSB 2359296   // bf16 [2048][576]   (294912 fl)
#define OFF_AU     2654208   // bf16 [12][2048][32] (393216 fl)
#define OFF_KU     3047424   // bf16 [12][2048][32] (393216 fl)
#define OFF_VU     3440640   // bf16 [12][48][2048] (589824 fl)
#define WS_FLOATS  4030464

__device__ __forceinline__ ushort_t bfr(float x) {   // fp32 -> bf16 bits, RNE
    union { float f; uint32_t u; } v; v.f = x;
    uint32_t r = v.u + 0x7FFFu + ((v.u >> 16) & 1u);
    return (ushort_t)(r >> 16);
}

__device__ __forceinline__ uint32_t pack2(float a, float b) {
    return (uint32_t)bfr(a) | ((uint32_t)bfr(b) << 16);
}

// ---------------------------------------------------------------------------
// gemm_proj: Pall[m][n] = sum_k s[m][k]*Wcat[n][k] + bcat[n].
// BM=128, BN=64, BK=32; fp32->bf16 conversion fused into LDS staging;
// weight concat (Wq|Wkv|Wqp|Wkvp rows) resolved piecewise per staged row.
// MFMA core + fragment layout verified r7/r8.
// ---------------------------------------------------------------------------
__global__ __launch_bounds__(256) void gemm_proj(
    const float* __restrict__ s,
    const float* __restrict__ Wq, const float* __restrict__ Wkv,
    const float* __restrict__ Wqp, const float* __restrict__ Wkvp,
    const float* __restrict__ bq, const float* __restrict__ bkv,
    const float* __restrict__ bqp, const float* __restrict__ bkvp,
    float* __restrict__ C)
{
    __shared__ ushort_t As[128][40];
    __shared__ ushort_t Bs[64][40];

    const int bm = blockIdx.y * 128;
    const int bn = blockIdx.x * 64;
    const int t  = threadIdx.x;
    const int w  = t >> 6, lane = t & 63;
    const int m  = lane & 15, quad = lane >> 4;
    const int wm = (w >> 1) * 64, wn = (w & 1) * 32;

    f4_t acc[4][2];
    #pragma unroll
    for (int i2 = 0; i2 < 4; ++i2)
        #pragma unroll
        for (int j2 = 0; j2 < 2; ++j2)
            acc[i2][j2] = (f4_t){0.f, 0.f, 0.f, 0.f};

    for (int k0 = 0; k0 < 384; k0 += 32) {
        #pragma unroll
        for (int u = 0; u < 4; ++u) {          // A: 128 rows x 32 k fp32
            int e = t + u * 256;               // 0..1023
            int r = e >> 3, kk = (e & 7) * 4;
            float4 va = *(const float4*)&s[(size_t)(bm + r) * 384 + k0 + kk];
            uint2 pk; pk.x = pack2(va.x, va.y); pk.y = pack2(va.z, va.w);
            *(uint2*)&As[r][kk] = pk;
        }
        #pragma unroll
        for (int u = 0; u < 2; ++u) {          // B: 64 rows x 32 k fp32, concat
            int e = t + u * 256;               // 0..511
            int r = e >> 3, kk = (e & 7) * 4;
            int rr = bn + r;
            const float* wp;
            if (rr < 192)      wp = Wq   + (size_t)rr * 384;
            else if (rr < 576) wp = Wkv  + (size_t)(rr - 192) * 384;
            else if (rr < 720) wp = Wqp  + (size_t)(rr - 576) * 384;
            else               wp = Wkvp + (size_t)(rr - 720) * 384;
            float4 vb = *(const float4*)&wp[k0 + kk];
            uint2 pk; pk.x = pack2(vb.x, vb.y); pk.y = pack2(vb.z, vb.w);
            *(uint2*)&Bs[r][kk] = pk;
        }
        __syncthreads();
        bf8_t af[4], bfv[2];
        #pragma unroll
        for (int x = 0; x < 4; ++x) af[x]  = *(const bf8_t*)&As[wm + x * 16 + m][quad * 8];
        #pragma unroll
        for (int x = 0; x < 2; ++x) bfv[x] = *(const bf8_t*)&Bs[wn + x * 16 + m][quad * 8];
        #pragma unroll
        for (int i2 = 0; i2 < 4; ++i2)
            #pragma unroll
            for (int j2 = 0; j2 < 2; ++j2)
                acc[i2][j2] = __builtin_amdgcn_mfma_f32_16x16x32_bf16(
                    af[i2], bfv[j2], acc[i2][j2], 0, 0, 0);
        __syncthreads();
    }

    #pragma unroll
    for (int j2 = 0; j2 < 2; ++j2) {
        int col = bn + wn + j2 * 16 + m;
        float bb = (col < 192) ? bq[col] : (col < 576) ? bkv[col - 192]
                 : (col < 720) ? bqp[col - 576] : bkvp[col - 720];
        #pragma unroll
        for (int i2 = 0; i2 < 4; ++i2)
            #pragma unroll
            for (int r = 0; r < 4; ++r) {
                int row = bm + wm + i2 * 16 + quad * 4 + r;
                C[(size_t)row * PSTR + col] = acc[i2][j2][r] + bb;
            }
    }
}

// ---------------------------------------------------------------------------
// gemm_out: out[m][n] = sum_k featsb[m][k]*Wout[n][k] + bout[n].
// BM=BN=64, K=576. A already bf16; Wout converted in staging.
// ---------------------------------------------------------------------------
__global__ __launch_bounds__(256) void gemm_out(
    const ushort_t* __restrict__ A, const float* __restrict__ Wout,
    const float* __restrict__ bout, float* __restrict__ C)
{
    __shared__ ushort_t As[64][40];
    __shared__ ushort_t Bs[64][40];

    const int bm = blockIdx.y * 64;
    const int bn = blockIdx.x * 64;
    const int t  = threadIdx.x;
    const int w  = t >> 6, lane = t & 63;
    const int m  = lane & 15, quad = lane >> 4;
    const int wm = (w >> 1) * 32, wn = (w & 1) * 32;

    f4_t acc[2][2];
    #pragma unroll
    for (int i2 = 0; i2 < 2; ++i2)
        #pragma unroll
        for (int j2 = 0; j2 < 2; ++j2)
            acc[i2][j2] = (f4_t){0.f, 0.f, 0.f, 0.f};

    for (int k0 = 0; k0 < 576; k0 += 32) {
        {
            int r = t >> 2, kk = (t & 3) * 8;   // A bf16 direct: 64x32
            *(uint4*)&As[r][kk] = *(const uint4*)&A[(size_t)(bm + r) * 576 + k0 + kk];
        }
        #pragma unroll
        for (int u = 0; u < 2; ++u) {           // B fp32 -> bf16: 64x32
            int e = t + u * 256;
            int r = e >> 3, kk = (e & 7) * 4;
            float4 vb = *(const float4*)&Wout[(size_t)(bn + r) * 576 + k0 + kk];
            uint2 pk; pk.x = pack2(vb.x, vb.y); pk.y = pack2(vb.z, vb.w);
            *(uint2*)&Bs[r][kk] = pk;
        }
        __syncthreads();
        bf8_t af[2], bfv[2];
        #pragma unroll
        for (int x = 0; x < 2; ++x) {
            af[x]  = *(const bf8_t*)&As[wm + x * 16 + m][quad * 8];
            bfv[x] = *(const bf8_t*)&Bs[wn + x * 16 + m][quad * 8];
        }
        #pragma unroll
        for (int i2 = 0; i2 < 2; ++i2)
            #pragma unroll
            for (int j2 = 0; j2 < 2; ++j2)
                acc[i2][j2] = __builtin_amdgcn_mfma_f32_16x16x32_bf16(
                    af[i2], bfv[j2], acc[i2][j2], 0, 0, 0);
        __syncthreads();
    }

    #pragma unroll
    for (int j2 = 0; j2 < 2; ++j2) {
        int col = bn + wn + j2 * 16 + m;
        float bb = bout[col];
        #pragma unroll
        for (int i2 = 0; i2 < 2; ++i2)
            #pragma unroll
            for (int r = 0; r < 4; ++r) {
                int row = bm + wm + i2 * 16 + quad * 4 + r;
                C[(size_t)row * 384 + col] = acc[i2][j2][r] + bb;
            }
    }
}

// ---------------------------------------------------------------------------
// pack_aug (verified r8): LDS-staged coalesced reads; per-(n,h) rotation +
// augmented A/K/V operand construction.
// ---------------------------------------------------------------------------
__global__ __launch_bounds__(128) void pack_aug(
    const float* __restrict__ Pall, const float* __restrict__ rot,
    const float* __restrict__ trans, const float* __restrict__ mask,
    const float* __restrict__ hwv,
    ushort_t* __restrict__ AU, ushort_t* __restrict__ KU,
    ushort_t* __restrict__ VU)
{
    __shared__ float S[8][1156];
    const int n0 = blockIdx.x * 8;
    const int t  = threadIdx.x;

    #pragma unroll
    for (int u = 0; u < 18; ++u) {
        int f = t + u * 128;
        int rr = f / 288, c4 = f % 288;
        float4 v = *(const float4*)&Pall[(size_t)(n0 + rr) * PSTR + c4 * 4];
        *(float4*)&S[rr][c4 * 4] = v;
    }
    __syncthreads();

    if (t >= 96) return;
    const int nl = t & 7, h = t >> 3;
    const int n  = n0 + nl;
    const float* row = S[nl];

    const float whw = 0.5f * logf(1.0f + expf(hwv[h])) * 0.13608276348795434f;
    const float scale_a = 0.14433756729740643f;   // sqrt(1/48)

    float R[9], T[3];
    #pragma unroll
    for (int z = 0; z < 9; ++z) R[z] = rot[(size_t)n * 9 + z];
    #pragma unroll
    for (int d = 0; d < 3; ++d) T[d] = trans[(size_t)n * 3 + d];

    float qpv[12], q2 = 0.f;
    #pragma unroll
    for (int p = 0; p < 4; ++p) {
        float r0 = row[576 +   0 + h * 4 + p];
        float r1 = row[576 +  48 + h * 4 + p];
        float r2 = row[576 +  96 + h * 4 + p];
        #pragma unroll
        for (int d = 0; d < 3; ++d) {
            float o = R[d*3+0]*r0 + R[d*3+1]*r1 + R[d*3+2]*r2 + T[d];
            qpv[p * 3 + d] = o;
            q2 += o * o;
        }
    }

    float kpv[12], vpv[24], k2 = 0.f;
    #pragma unroll
    for (int pt = 0; pt < 12; ++pt) {
        float r0 = row[720 +   0 + h * 12 + pt];
        float r1 = row[720 + 144 + h * 12 + pt];
        float r2 = row[720 + 288 + h * 12 + pt];
        #pragma unroll
        for (int d = 0; d < 3; ++d) {
            float o = R[d*3+0]*r0 + R[d*3+1]*r1 + R[d*3+2]*r2 + T[d];
            if (pt < 4) { kpv[pt * 3 + d] = o; k2 += o * o; }
            else        { vpv[(pt - 4) * 3 + d] = o; }
        }
    }

    const float mi = mask[n];

    __align__(16) ushort_t a32[32];
    #pragma unroll
    for (int c = 0; c < 16; ++c) a32[c] = bfr(row[h * 16 + c] * scale_a);
    #pragma unroll
    for (int z = 0; z < 12; ++z) a32[16 + z] = bfr(qpv[z] * (2.0f * whw));
    a32[28] = bfr(-whw);
    a32[29] = bfr(-whw * q2);
    a32[30] = bfr(mi * MASKV);
    a32[31] = bfr(-MASKV);
    ushort_t* adst = AU + ((size_t)h * Nseq + n) * 32;
    #pragma unroll
    for (int u = 0; u < 4; ++u) ((uint4*)adst)[u] = ((const uint4*)a32)[u];

    const float* kvrow = row + 192 + h * 32;
    __align__(16) ushort_t k32[32];
    #pragma unroll
    for (int c = 0; c < 16; ++c) k32[c] = bfr(kvrow[c]);
    #pragma unroll
    for (int z = 0; z < 12; ++z) k32[16 + z] = bfr(kpv[z]);
    k32[28] = bfr(k2);
    k32[29] = 0x3F80;
    k32[30] = bfr(mi);
    k32[31] = 0x3F80;
    ushort_t* kdst = KU + ((size_t)h * Nseq + n) * 32;
    #pragma unroll
    for (int u = 0; u < 4; ++u) ((uint4*)kdst)[u] = ((const uint4*)k32)[u];

    ushort_t* vb = VU + (size_t)h * 48 * Nseq + n;
    #pragma unroll
    for (int c = 0; c < 16; ++c) vb[(size_t)c * Nseq] = bfr(kvrow[16 + c]);
    #pragma unroll
    for (int z = 0; z < 24; ++z) vb[(size_t)(16 + z) * Nseq] = bfr(vpv[z]);
    vb[(size_t)40 * Nseq] = 0x3F80;
    #pragma unroll
    for (int c = 41; c < 48; ++c) vb[(size_t)c * Nseq] = 0;
}

__device__ __forceinline__ bf8_t expack(f4_t s) {   // exp -> bf16 low4, zero high
    s4_t p;
    p[0] = (short)bfr(__expf(s[0]));
    p[1] = (short)bfr(__expf(s[1]));
    p[2] = (short)bfr(__expf(s[2]));
    p[3] = (short)bfr(__expf(s[3]));
    s4_t z = (s4_t)0;
    return __builtin_shufflevector(p, z, 0, 1, 2, 3, 4, 5, 6, 7);
}

__device__ __forceinline__ bf8_t vpad(s4_t v) {     // V low4, zero high
    s4_t z = (s4_t)0;
    return __builtin_shufflevector(v, z, 0, 1, 2, 3, 4, 5, 6, 7);
}

struct KVTile { bf8_t kb0, kb1; s4_t v[6]; };   // 20 VGPRs

__device__ __forceinline__ KVTile load_tile(
    const ushort_t* __restrict__ kb_base, const ushort_t* __restrict__ v_base,
    int j32)
{
    KVTile tl;
    tl.kb0  = *(const bf8_t*)(kb_base + (size_t)j32 * 32);
    tl.kb1  = *(const bf8_t*)(kb_base + (size_t)(j32 + 16) * 32);
    tl.v[0] = *(const s4_t*)(v_base + j32);
    tl.v[1] = *(const s4_t*)(v_base + 16 * Nseq + j32);
    tl.v[2] = *(const s4_t*)(v_base + 32 * Nseq + j32);
    tl.v[3] = *(const s4_t*)(v_base + j32 + 16);
    tl.v[4] = *(const s4_t*)(v_base + 16 * Nseq + j32 + 16);
    tl.v[5] = *(const s4_t*)(v_base + 32 * Nseq + j32 + 16);
    return tl;
}

// ---------------------------------------------------------------------------
// MFMA attention v4 (r8-verified math, software-pipelined): tile jt+1's K/V
// loads issue before tile jt's exp/PV chain; full unroll so the scheduler
// keeps 8 loads in flight across ~180 cyc of compute. No LDS in the j-loop.
// ---------------------------------------------------------------------------
__global__ __launch_bounds__(256, 3) void attn_mfma(
    const ushort_t* __restrict__ AU, const ushort_t* __restrict__ KU,
    const ushort_t* __restrict__ VU,
    const float* __restrict__ rot, const float* __restrict__ trans,
    ushort_t* __restrict__ featsb)
{
    __shared__ float red[4][32][49];   // 25088 B

    const int b    = blockIdx.x;
    const int h    = b >> 6;
    const int ib   = b & 63;
    const int t    = threadIdx.x;
    const int w    = t >> 6;
    const int lane = t & 63;
    const int m    = lane & 15;
    const int quad = lane >> 4;
    const int i0   = ib * 32;

    bf8_t afA = *(const bf8_t*)(AU + ((size_t)h * Nseq + i0 +      m) * 32 + quad * 8);
    bf8_t afB = *(const bf8_t*)(AU + ((size_t)h * Nseq + i0 + 16 + m) * 32 + quad * 8);

    f4_t acc[6];
    #pragma unroll
    for (int z = 0; z < 6; ++z) acc[z] = (f4_t){0.f, 0.f, 0.f, 0.f};

    const int jb0 = w * 512;
    const ushort_t* kb_base = KU + ((size_t)h * Nseq + jb0 + m) * 32 + quad * 8;
    const ushort_t* v_base  = VU + ((size_t)h * 48 + m) * Nseq + jb0 + quad * 4;

    KVTile cur = load_tile(kb_base, v_base, 0);

    #pragma unroll
    for (int jt = 0; jt < 16; ++jt) {
        // QK on current tile (operand swap -> S^T, r8-verified)
        f4_t zz = (f4_t){0.f, 0.f, 0.f, 0.f};
        f4_t sXA = __builtin_amdgcn_mfma_f32_16x16x32_bf16(cur.kb0, afA, zz, 0, 0, 0);
        f4_t sXB = __builtin_amdgcn_mfma_f32_16x16x32_bf16(cur.kb0, afB, zz, 0, 0, 0);
        f4_t sYA = __builtin_amdgcn_mfma_f32_16x16x32_bf16(cur.kb1, afA, zz, 0, 0, 0);
        f4_t sYB = __builtin_amdgcn_mfma_f32_16x16x32_bf16(cur.kb1, afB, zz, 0, 0, 0);

        // prefetch next tile (compile-time guard; loads overlap exp+PV below)
        KVTile nxt;
        if (jt < 15) nxt = load_tile(kb_base, v_base, (jt + 1) * 32);

        bf8_t pXA = expack(sXA), pXB = expack(sXB);
        bf8_t pYA = expack(sYA), pYB = expack(sYB);
        bf8_t f0 = vpad(cur.v[0]), f1 = vpad(cur.v[1]), f2 = vpad(cur.v[2]);
        bf8_t g0 = vpad(cur.v[3]), g1 = vpad(cur.v[4]), g2 = vpad(cur.v[5]);

        acc[0] = __builtin_amdgcn_mfma_f32_16x16x32_bf16(pXA, f0, acc[0], 0, 0, 0);
        acc[0] = __builtin_amdgcn_mfma_f32_16x16x32_bf16(pYA, g0, acc[0], 0, 0, 0);
        acc[1] = __builtin_amdgcn_mfma_f32_16x16x32_bf16(pXA, f1, acc[1], 0, 0, 0);
        acc[1] = __builtin_amdgcn_mfma_f32_16x16x32_bf16(pYA, g1, acc[1], 0, 0, 0);
        acc[2] = __builtin_amdgcn_mfma_f32_16x16x32_bf16(pXA, f2, acc[2], 0, 0, 0);
        acc[2] = __builtin_amdgcn_mfma_f32_16x16x32_bf16(pYA, g2, acc[2], 0, 0, 0);
        acc[3] = __builtin_amdgcn_mfma_f32_16x16x32_bf16(pXB, f0, acc[3], 0, 0, 0);
        acc[3] = __builtin_amdgcn_mfma_f32_16x16x32_bf16(pYB, g0, acc[3], 0, 0, 0);
        acc[4] = __builtin_amdgcn_mfma_f32_16x16x32_bf16(pXB, f1, acc[4], 0, 0, 0);
        acc[4] = __builtin_amdgcn_mfma_f32_16x16x32_bf16(pYB, g1, acc[4], 0, 0, 0);
        acc[5] = __builtin_amdgcn_mfma_f32_16x16x32_bf16(pXB, f2, acc[5], 0, 0, 0);
        acc[5] = __builtin_amdgcn_mfma_f32_16x16x32_bf16(pYB, g2, acc[5], 0, 0, 0);

        cur = nxt;
    }

    #pragma unroll
    for (int r = 0; r < 4; ++r) {
        red[w][quad * 4 + r][m]           = acc[0][r];
        red[w][quad * 4 + r][16 + m]      = acc[1][r];
        red[w][quad * 4 + r][32 + m]      = acc[2][r];
        red[w][16 + quad * 4 + r][m]      = acc[3][r];
        red[w][16 + quad * 4 + r][16 + m] = acc[4][r];
        red[w][16 + quad * 4 + r][32 + m] = acc[5][r];
    }
    __syncthreads();

    #pragma unroll
    for (int u = 0; u < 6; ++u) {
        int e = t + u * 256;
        int rr = e / 48, cc = e % 48;
        red[0][rr][cc] = red[0][rr][cc] + red[1][rr][cc] + red[2][rr][cc] + red[3][rr][cc];
    }
    __syncthreads();

    if (t < 32) {
        const int i = i0 + t;
        float L   = red[0][t][40];
        float inv = 1.0f / L;
        float o[40];
        #pragma unroll
        for (int z = 0; z < 40; ++z) o[z] = red[0][t][z] * inv;

        ushort_t* f = featsb + (size_t)i * 576;
        #pragma unroll
        for (int c = 0; c < 16; ++c) f[h * 16 + c] = bfr(o[c]);

        float R[9], T[3];
        #pragma unroll
        for (int z = 0; z < 9; ++z) R[z] = rot[(size_t)i * 9 + z];
        #pragma unroll
        for (int d = 0; d < 3; ++d) T[d] = trans[(size_t)i * 3 + d];

        #pragma unroll
        for (int p8 = 0; p8 < 8; ++p8) {
            float g0 = o[16 + p8 * 3 + 0] - T[0];
            float g1 = o[16 + p8 * 3 + 1] - T[1];
            float g2 = o[16 + p8 * 3 + 2] - T[2];
            float xx = R[0] * g0 + R[3] * g1 + R[6] * g2;
            float yy = R[1] * g0 + R[4] * g1 + R[7] * g2;
            float zz = R[2] * g0 + R[5] * g1 + R[8] * g2;
            float dist = sqrtf(xx * xx + yy * yy + zz * zz + EPSm);
            f[192 + h * 8 + p8] = bfr(xx);
            f[288 + h * 8 + p8] = bfr(yy);
            f[384 + h * 8 + p8] = bfr(zz);
            f[480 + h * 8 + p8] = bfr(dist);
        }
    }
}

// ---------------------------------------------------------------------------
extern "C" void kernel_launch(void* const* d_in, const int* in_sizes, int n_in,
                              void* d_out, int out_size, void* d_ws, size_t ws_size,
                              hipStream_t stream)
{
    const float* s     = (const float*)d_in[0];
    const float* rot   = (const float*)d_in[1];
    const float* trans = (const float*)d_in[2];
    const float* mask  = (const float*)d_in[3];
    const float* Wq    = (const float*)d_in[4];
    const float* bq    = (const float*)d_in[5];
    const float* Wkv   = (const float*)d_in[6];
    const float* bkv   = (const float*)d_in[7];
    const float* Wqp   = (const float*)d_in[8];
    const float* bqp   = (const float*)d_in[9];
    const float* Wkvp  = (const float*)d_in[10];
    const float* bkvp  = (const float*)d_in[11];
    const float* hwv   = (const float*)d_in[12];
    const float* Wout  = (const float*)d_in[13];
    const float* bout  = (const float*)d_in[14];
    float* out = (float*)d_out;
    float* ws  = (float*)d_ws;

    if (ws_size < (size_t)WS_FLOATS * sizeof(float)) return;

    float*    Pall   = ws + OFF_PALL;
    ushort_t* featsb = (ushort_t*)(ws + OFF_FEATSB);
    ushort_t* AU     = (ushort_t*)(ws + OFF_AU);
    ushort_t* KU     = (ushort_t*)(ws + OFF_KU);
    ushort_t* VU     = (ushort_t*)(ws + OFF_VU);

    gemm_proj<<<dim3(1152 / 64, 2048 / 128), 256, 0, stream>>>(
        s, Wq, Wkv, Wqp, Wkvp, bq, bkv, bqp, bkvp, Pall);

    pack_aug<<<dim3(256), 128, 0, stream>>>(Pall, rot, trans, mask, hwv,
                                            AU, KU, VU);

    attn_mfma<<<dim3(768), 256, 0, stream>>>(AU, KU, VU, rot, trans, featsb);

    gemm_out<<<dim3(384 / 64, 2048 / 64), 256, 0, stream>>>(
        featsb, Wout, bout, out);
}

// Round 11
// 139.804 us; speedup vs baseline: 1.3046x; 1.3046x over previous
//
#include <hip/hip_runtime.h>
#include <hip/hip_bf16.h>
#include <cstdint>
#include <cstddef>

// Problem constants
#define Hh    12
#define Nseq  2048
#define PSTR  1152      // concat projection width: 192 q | 384 kv | 144 qp | 432 kvp
#define EPSm  1e-8f
#define MASKV 1024.0f   // (mi*M)*mj + (-M)*1 == 0 exactly when masks==1

typedef unsigned short ushort_t;
typedef __attribute__((ext_vector_type(8))) short bf8_t;   // 8 bf16 (4 VGPRs)
typedef __attribute__((ext_vector_type(4))) short s4_t;    // 4 bf16 (2 VGPRs)
typedef __attribute__((ext_vector_type(4))) float f4_t;    // MFMA C/D

// ws offsets (floats). Total 5,051,520 fl = 20.2 MB <= proven 29.1 MB budget.
#define OFF_PALL   0         // fp32 [2048][1152]
#define OFF_WALLB  2359296   // bf16 [1152][384]
#define OFF_BALL   2580480   // fp32 [1152]
#define OFF_SB     2581632   // bf16 [2048][384]
#define OFF_WOUTB  2974848   // bf16 [384][576]
#define OFF_FEATSB 3085440   // bf16 [2048][576]
#define OFF_AU     3675264   // bf16 [12][2048][32]
#define OFF_KU     4068480   // bf16 [12][2048][32]
#define OFF_VU     4461696   // bf16 [12][64][48][32]  TILE-BLOCKED (589824 fl)
#define WS_FLOATS  5051520

__device__ __forceinline__ ushort_t bfr(float x) {   // fp32 -> bf16 bits, RNE
    union { float f; uint32_t u; } v; v.f = x;
    uint32_t r = v.u + 0x7FFFu + ((v.u >> 16) & 1u);
    return (ushort_t)(r >> 16);
}

// ---------------------------------------------------------------------------
// prep (verified r7/r8): concat weights -> bf16, biases -> fp32, s/Wout bf16.
// ---------------------------------------------------------------------------
__global__ __launch_bounds__(256) void prep(
    const float* __restrict__ s, const float* __restrict__ Wout,
    const float* __restrict__ Wq, const float* __restrict__ Wkv,
    const float* __restrict__ Wqp, const float* __restrict__ Wkvp,
    const float* __restrict__ bq, const float* __restrict__ bkv,
    const float* __restrict__ bqp, const float* __restrict__ bkvp,
    ushort_t* __restrict__ Wallb, float* __restrict__ ball,
    ushort_t* __restrict__ sb, ushort_t* __restrict__ Woutb)
{
    int idx = blockIdx.x * 256 + threadIdx.x;
    if (idx < 1152 * 384) {
        int r = idx / 384, c = idx % 384;
        float v;
        if (r < 192)      v = Wq [(size_t)r * 384 + c];
        else if (r < 576) v = Wkv[(size_t)(r - 192) * 384 + c];
        else if (r < 720) v = Wqp[(size_t)(r - 576) * 384 + c];
        else              v = Wkvp[(size_t)(r - 720) * 384 + c];
        Wallb[idx] = bfr(v);
    }
    if (idx < 1152) {
        float v;
        if (idx < 192)      v = bq[idx];
        else if (idx < 576) v = bkv[idx - 192];
        else if (idx < 720) v = bqp[idx - 576];
        else                v = bkvp[idx - 720];
        ball[idx] = v;
    }
    if (idx < 2048 * 384) sb[idx] = bfr(s[idx]);
    if (idx < 384 * 576)  Woutb[idx] = bfr(Wout[idx]);
}

// ---------------------------------------------------------------------------
// bf16 MFMA GEMM (verified r8). C[m][n] = sum_k A[m][k]*W[n][k] + bias[n].
// ---------------------------------------------------------------------------
template<int BM, int BN>
__global__ __launch_bounds__(256) void gemm_mfma(
    const ushort_t* __restrict__ A, const ushort_t* __restrict__ W,
    const float* __restrict__ bias, float* __restrict__ C,
    int M, int Nn, int K)
{
    constexpr int WM = BM / 2, WN = BN / 2;
    constexpr int MI = WM / 16, NJ = WN / 16;
    __shared__ ushort_t As[BM][40];
    __shared__ ushort_t Bs[BN][40];

    const int bm = blockIdx.y * BM;
    const int bn = blockIdx.x * BN;
    const int t  = threadIdx.x;
    const int w  = t >> 6, lane = t & 63;
    const int m  = lane & 15, quad = lane >> 4;
    const int wm = (w >> 1) * WM, wn = (w & 1) * WN;

    f4_t acc[MI][NJ];
    #pragma unroll
    for (int i2 = 0; i2 < MI; ++i2)
        #pragma unroll
        for (int j2 = 0; j2 < NJ; ++j2)
            acc[i2][j2] = (f4_t){0.f, 0.f, 0.f, 0.f};

    for (int k0 = 0; k0 < K; k0 += 32) {
        #pragma unroll
        for (int u = 0; u < BM / 64; ++u) {
            int e = t + u * 256;
            int r = e >> 2, kk = (e & 3) * 8;
            *(uint4*)&As[r][kk] = *(const uint4*)&A[(size_t)(bm + r) * K + k0 + kk];
        }
        #pragma unroll
        for (int u = 0; u < BN / 64; ++u) {
            int e = t + u * 256;
            int r = e >> 2, kk = (e & 3) * 8;
            *(uint4*)&Bs[r][kk] = *(const uint4*)&W[(size_t)(bn + r) * K + k0 + kk];
        }
        __syncthreads();
        bf8_t af[MI], bfv[NJ];
        #pragma unroll
        for (int x = 0; x < MI; ++x) af[x]  = *(const bf8_t*)&As[wm + x * 16 + m][quad * 8];
        #pragma unroll
        for (int x = 0; x < NJ; ++x) bfv[x] = *(const bf8_t*)&Bs[wn + x * 16 + m][quad * 8];
        #pragma unroll
        for (int i2 = 0; i2 < MI; ++i2)
            #pragma unroll
            for (int j2 = 0; j2 < NJ; ++j2)
                acc[i2][j2] = __builtin_amdgcn_mfma_f32_16x16x32_bf16(
                    af[i2], bfv[j2], acc[i2][j2], 0, 0, 0);
        __syncthreads();
    }

    #pragma unroll
    for (int j2 = 0; j2 < NJ; ++j2) {
        int col = bn + wn + j2 * 16 + m;
        float bb = bias[col];
        #pragma unroll
        for (int i2 = 0; i2 < MI; ++i2)
            #pragma unroll
            for (int r = 0; r < 4; ++r) {
                int row = bm + wm + i2 * 16 + quad * 4 + r;
                C[(size_t)row * Nn + col] = acc[i2][j2][r] + bb;
            }
    }
}

// ---------------------------------------------------------------------------
// pack_aug (r8-verified math). VU now TILE-BLOCKED: [h][j>>5][c][j&31] so the
// attention V-fragment loads are dense (each 32-j tile = contiguous 3 KB).
// ---------------------------------------------------------------------------
__global__ __launch_bounds__(128) void pack_aug(
    const float* __restrict__ Pall, const float* __restrict__ rot,
    const float* __restrict__ trans, const float* __restrict__ mask,
    const float* __restrict__ hwv,
    ushort_t* __restrict__ AU, ushort_t* __restrict__ KU,
    ushort_t* __restrict__ VU)
{
    __shared__ float S[8][1156];
    const int n0 = blockIdx.x * 8;
    const int t  = threadIdx.x;

    #pragma unroll
    for (int u = 0; u < 18; ++u) {
        int f = t + u * 128;
        int rr = f / 288, c4 = f % 288;
        float4 v = *(const float4*)&Pall[(size_t)(n0 + rr) * PSTR + c4 * 4];
        *(float4*)&S[rr][c4 * 4] = v;
    }
    __syncthreads();

    if (t >= 96) return;
    const int nl = t & 7, h = t >> 3;
    const int n  = n0 + nl;
    const float* row = S[nl];

    const float whw = 0.5f * logf(1.0f + expf(hwv[h])) * 0.13608276348795434f;
    const float scale_a = 0.14433756729740643f;   // sqrt(1/48)

    float R[9], T[3];
    #pragma unroll
    for (int z = 0; z < 9; ++z) R[z] = rot[(size_t)n * 9 + z];
    #pragma unroll
    for (int d = 0; d < 3; ++d) T[d] = trans[(size_t)n * 3 + d];

    float qpv[12], q2 = 0.f;
    #pragma unroll
    for (int p = 0; p < 4; ++p) {
        float r0 = row[576 +   0 + h * 4 + p];
        float r1 = row[576 +  48 + h * 4 + p];
        float r2 = row[576 +  96 + h * 4 + p];
        #pragma unroll
        for (int d = 0; d < 3; ++d) {
            float o = R[d*3+0]*r0 + R[d*3+1]*r1 + R[d*3+2]*r2 + T[d];
            qpv[p * 3 + d] = o;
            q2 += o * o;
        }
    }

    float kpv[12], vpv[24], k2 = 0.f;
    #pragma unroll
    for (int pt = 0; pt < 12; ++pt) {
        float r0 = row[720 +   0 + h * 12 + pt];
        float r1 = row[720 + 144 + h * 12 + pt];
        float r2 = row[720 + 288 + h * 12 + pt];
        #pragma unroll
        for (int d = 0; d < 3; ++d) {
            float o = R[d*3+0]*r0 + R[d*3+1]*r1 + R[d*3+2]*r2 + T[d];
            if (pt < 4) { kpv[pt * 3 + d] = o; k2 += o * o; }
            else        { vpv[(pt - 4) * 3 + d] = o; }
        }
    }

    const float mi = mask[n];

    __align__(16) ushort_t a32[32];
    #pragma unroll
    for (int c = 0; c < 16; ++c) a32[c] = bfr(row[h * 16 + c] * scale_a);
    #pragma unroll
    for (int z = 0; z < 12; ++z) a32[16 + z] = bfr(qpv[z] * (2.0f * whw));
    a32[28] = bfr(-whw);
    a32[29] = bfr(-whw * q2);
    a32[30] = bfr(mi * MASKV);
    a32[31] = bfr(-MASKV);
    ushort_t* adst = AU + ((size_t)h * Nseq + n) * 32;
    #pragma unroll
    for (int u = 0; u < 4; ++u) ((uint4*)adst)[u] = ((const uint4*)a32)[u];

    const float* kvrow = row + 192 + h * 32;
    __align__(16) ushort_t k32[32];
    #pragma unroll
    for (int c = 0; c < 16; ++c) k32[c] = bfr(kvrow[c]);
    #pragma unroll
    for (int z = 0; z < 12; ++z) k32[16 + z] = bfr(kpv[z]);
    k32[28] = bfr(k2);
    k32[29] = 0x3F80;
    k32[30] = bfr(mi);
    k32[31] = 0x3F80;
    ushort_t* kdst = KU + ((size_t)h * Nseq + n) * 32;
    #pragma unroll
    for (int u = 0; u < 4; ++u) ((uint4*)kdst)[u] = ((const uint4*)k32)[u];

    // TILE-BLOCKED V: element (h, j=n, c) at h*98304 + (n>>5)*1536 + c*32 + (n&31)
    ushort_t* vb = VU + (size_t)h * 98304 + (size_t)(n >> 5) * 1536 + (n & 31);
    #pragma unroll
    for (int c = 0; c < 16; ++c) vb[c * 32] = bfr(kvrow[16 + c]);
    #pragma unroll
    for (int z = 0; z < 24; ++z) vb[(16 + z) * 32] = bfr(vpv[z]);
    vb[40 * 32] = 0x3F80;
    #pragma unroll
    for (int c = 41; c < 48; ++c) vb[c * 32] = 0;
}

__device__ __forceinline__ bf8_t expack(f4_t s) {   // exp -> bf16 low4, zero high
    s4_t p;
    p[0] = (short)bfr(__expf(s[0]));
    p[1] = (short)bfr(__expf(s[1]));
    p[2] = (short)bfr(__expf(s[2]));
    p[3] = (short)bfr(__expf(s[3]));
    s4_t z = (s4_t)0;
    return __builtin_shufflevector(p, z, 0, 1, 2, 3, 4, 5, 6, 7);
}

__device__ __forceinline__ bf8_t vpad(s4_t v) {     // V low4, zero high
    s4_t z = (s4_t)0;
    return __builtin_shufflevector(v, z, 0, 1, 2, 3, 4, 5, 6, 7);
}

struct KVTile { bf8_t kb0, kb1; s4_t v[6]; };

// Tile loads. V now dense: tile base + c-block*512 + m*32 (+16 for j 16-31),
// 8 B per lane -> the 6 loads together consume exactly the contiguous 3 KB tile.
__device__ __forceinline__ KVTile load_tile(
    const ushort_t* __restrict__ kb_base, const ushort_t* __restrict__ vt,
    int m, int quad)
{
    KVTile tl;
    tl.kb0  = *(const bf8_t*)(kb_base);
    tl.kb1  = *(const bf8_t*)(kb_base + 16 * 32);
    tl.v[0] = *(const s4_t*)(vt +        m * 32 +      quad * 4);
    tl.v[1] = *(const s4_t*)(vt +  512 + m * 32 +      quad * 4);
    tl.v[2] = *(const s4_t*)(vt + 1024 + m * 32 +      quad * 4);
    tl.v[3] = *(const s4_t*)(vt +        m * 32 + 16 + quad * 4);
    tl.v[4] = *(const s4_t*)(vt +  512 + m * 32 + 16 + quad * 4);
    tl.v[5] = *(const s4_t*)(vt + 1024 + m * 32 + 16 + quad * 4);
    return tl;
}

// ---------------------------------------------------------------------------
// MFMA attention (r8-verified math; V loads now dense via tile-blocked VU).
// Grid 768 = 12h x 64 iblocks(32); 4 waves split j (512 each); S^T trick,
// no LDS in j-loop; LDS sum-merge + fused epilogue.
// ---------------------------------------------------------------------------
__global__ __launch_bounds__(256, 3) void attn_mfma(
    const ushort_t* __restrict__ AU, const ushort_t* __restrict__ KU,
    const ushort_t* __restrict__ VU,
    const float* __restrict__ rot, const float* __restrict__ trans,
    ushort_t* __restrict__ featsb)
{
    __shared__ float red[4][32][49];   // 25088 B

    const int b    = blockIdx.x;
    const int h    = b >> 6;
    const int ib   = b & 63;
    const int t    = threadIdx.x;
    const int w    = t >> 6;
    const int lane = t & 63;
    const int m    = lane & 15;
    const int quad = lane >> 4;
    const int i0   = ib * 32;

    bf8_t afA = *(const bf8_t*)(AU + ((size_t)h * Nseq + i0 +      m) * 32 + quad * 8);
    bf8_t afB = *(const bf8_t*)(AU + ((size_t)h * Nseq + i0 + 16 + m) * 32 + quad * 8);

    f4_t acc[6];
    #pragma unroll
    for (int z = 0; z < 6; ++z) acc[z] = (f4_t){0.f, 0.f, 0.f, 0.f};

    const int jb0 = w * 512;
    const ushort_t* kb_base = KU + ((size_t)h * Nseq + jb0 + m) * 32 + quad * 8;
    const ushort_t* v_base  = VU + (size_t)h * 98304 + (size_t)jb0 * 48;  // (jb0>>5)*1536

    KVTile cur = load_tile(kb_base, v_base, m, quad);

    #pragma unroll
    for (int jt = 0; jt < 16; ++jt) {
        f4_t zz = (f4_t){0.f, 0.f, 0.f, 0.f};
        f4_t sXA = __builtin_amdgcn_mfma_f32_16x16x32_bf16(cur.kb0, afA, zz, 0, 0, 0);
        f4_t sXB = __builtin_amdgcn_mfma_f32_16x16x32_bf16(cur.kb0, afB, zz, 0, 0, 0);
        f4_t sYA = __builtin_amdgcn_mfma_f32_16x16x32_bf16(cur.kb1, afA, zz, 0, 0, 0);
        f4_t sYB = __builtin_amdgcn_mfma_f32_16x16x32_bf16(cur.kb1, afB, zz, 0, 0, 0);

        KVTile nxt;
        if (jt < 15)
            nxt = load_tile(kb_base + (size_t)(jt + 1) * 32 * 32,
                            v_base + (size_t)(jt + 1) * 1536, m, quad);

        bf8_t pXA = expack(sXA), pXB = expack(sXB);
        bf8_t pYA = expack(sYA), pYB = expack(sYB);
        bf8_t f0 = vpad(cur.v[0]), f1 = vpad(cur.v[1]), f2 = vpad(cur.v[2]);
        bf8_t g0 = vpad(cur.v[3]), g1 = vpad(cur.v[4]), g2 = vpad(cur.v[5]);

        acc[0] = __builtin_amdgcn_mfma_f32_16x16x32_bf16(pXA, f0, acc[0], 0, 0, 0);
        acc[0] = __builtin_amdgcn_mfma_f32_16x16x32_bf16(pYA, g0, acc[0], 0, 0, 0);
        acc[1] = __builtin_amdgcn_mfma_f32_16x16x32_bf16(pXA, f1, acc[1], 0, 0, 0);
        acc[1] = __builtin_amdgcn_mfma_f32_16x16x32_bf16(pYA, g1, acc[1], 0, 0, 0);
        acc[2] = __builtin_amdgcn_mfma_f32_16x16x32_bf16(pXA, f2, acc[2], 0, 0, 0);
        acc[2] = __builtin_amdgcn_mfma_f32_16x16x32_bf16(pYA, g2, acc[2], 0, 0, 0);
        acc[3] = __builtin_amdgcn_mfma_f32_16x16x32_bf16(pXB, f0, acc[3], 0, 0, 0);
        acc[3] = __builtin_amdgcn_mfma_f32_16x16x32_bf16(pYB, g0, acc[3], 0, 0, 0);
        acc[4] = __builtin_amdgcn_mfma_f32_16x16x32_bf16(pXB, f1, acc[4], 0, 0, 0);
        acc[4] = __builtin_amdgcn_mfma_f32_16x16x32_bf16(pYB, g1, acc[4], 0, 0, 0);
        acc[5] = __builtin_amdgcn_mfma_f32_16x16x32_bf16(pXB, f2, acc[5], 0, 0, 0);
        acc[5] = __builtin_amdgcn_mfma_f32_16x16x32_bf16(pYB, g2, acc[5], 0, 0, 0);

        cur = nxt;
    }

    #pragma unroll
    for (int r = 0; r < 4; ++r) {
        red[w][quad * 4 + r][m]           = acc[0][r];
        red[w][quad * 4 + r][16 + m]      = acc[1][r];
        red[w][quad * 4 + r][32 + m]      = acc[2][r];
        red[w][16 + quad * 4 + r][m]      = acc[3][r];
        red[w][16 + quad * 4 + r][16 + m] = acc[4][r];
        red[w][16 + quad * 4 + r][32 + m] = acc[5][r];
    }
    __syncthreads();

    #pragma unroll
    for (int u = 0; u < 6; ++u) {
        int e = t + u * 256;
        int rr = e / 48, cc = e % 48;
        red[0][rr][cc] = red[0][rr][cc] + red[1][rr][cc] + red[2][rr][cc] + red[3][rr][cc];
    }
    __syncthreads();

    if (t < 32) {
        const int i = i0 + t;
        float L   = red[0][t][40];
        float inv = 1.0f / L;
        float o[40];
        #pragma unroll
        for (int z = 0; z < 40; ++z) o[z] = red[0][t][z] * inv;

        ushort_t* f = featsb + (size_t)i * 576;
        #pragma unroll
        for (int c = 0; c < 16; ++c) f[h * 16 + c] = bfr(o[c]);

        float R[9], T[3];
        #pragma unroll
        for (int z = 0; z < 9; ++z) R[z] = rot[(size_t)i * 9 + z];
        #pragma unroll
        for (int d = 0; d < 3; ++d) T[d] = trans[(size_t)i * 3 + d];

        #pragma unroll
        for (int p8 = 0; p8 < 8; ++p8) {
            float g0 = o[16 + p8 * 3 + 0] - T[0];
            float g1 = o[16 + p8 * 3 + 1] - T[1];
            float g2 = o[16 + p8 * 3 + 2] - T[2];
            float xx = R[0] * g0 + R[3] * g1 + R[6] * g2;
            float yy = R[1] * g0 + R[4] * g1 + R[7] * g2;
            float zz = R[2] * g0 + R[5] * g1 + R[8] * g2;
            float dist = sqrtf(xx * xx + yy * yy + zz * zz + EPSm);
            f[192 + h * 8 + p8] = bfr(xx);
            f[288 + h * 8 + p8] = bfr(yy);
            f[384 + h * 8 + p8] = bfr(zz);
            f[480 + h * 8 + p8] = bfr(dist);
        }
    }
}

// ---------------------------------------------------------------------------
extern "C" void kernel_launch(void* const* d_in, const int* in_sizes, int n_in,
                              void* d_out, int out_size, void* d_ws, size_t ws_size,
                              hipStream_t stream)
{
    const float* s     = (const float*)d_in[0];
    const float* rot   = (const float*)d_in[1];
    const float* trans = (const float*)d_in[2];
    const float* mask  = (const float*)d_in[3];
    const float* Wq    = (const float*)d_in[4];
    const float* bq    = (const float*)d_in[5];
    const float* Wkv   = (const float*)d_in[6];
    const float* bkv   = (const float*)d_in[7];
    const float* Wqp   = (const float*)d_in[8];
    const float* bqp   = (const float*)d_in[9];
    const float* Wkvp  = (const float*)d_in[10];
    const float* bkvp  = (const float*)d_in[11];
    const float* hwv   = (const float*)d_in[12];
    const float* Wout  = (const float*)d_in[13];
    const float* bout  = (const float*)d_in[14];
    float* out = (float*)d_out;
    float* ws  = (float*)d_ws;

    if (ws_size < (size_t)WS_FLOATS * sizeof(float)) return;

    float*    Pall   = ws + OFF_PALL;
    ushort_t* Wallb  = (ushort_t*)(ws + OFF_WALLB);
    float*    ball   = ws + OFF_BALL;
    ushort_t* sb     = (ushort_t*)(ws + OFF_SB);
    ushort_t* Woutb  = (ushort_t*)(ws + OFF_WOUTB);
    ushort_t* featsb = (ushort_t*)(ws + OFF_FEATSB);
    ushort_t* AU     = (ushort_t*)(ws + OFF_AU);
    ushort_t* KU     = (ushort_t*)(ws + OFF_KU);
    ushort_t* VU     = (ushort_t*)(ws + OFF_VU);

    prep<<<dim3(3072), 256, 0, stream>>>(s, Wout, Wq, Wkv, Wqp, Wkvp,
                                         bq, bkv, bqp, bkvp,
                                         Wallb, ball, sb, Woutb);

    gemm_mfma<128, 64><<<dim3(1152 / 64, 2048 / 128), 256, 0, stream>>>(
        sb, Wallb, ball, Pall, 2048, 1152, 384);

    pack_aug<<<dim3(256), 128, 0, stream>>>(Pall, rot, trans, mask, hwv,
                                            AU, KU, VU);

    attn_mfma<<<dim3(768), 256, 0, stream>>>(AU, KU, VU, rot, trans, featsb);

    gemm_mfma<64, 64><<<dim3(384 / 64, 2048 / 64), 256, 0, stream>>>(
        featsb, Woutb, bout, out, 2048, 384, 576);
}

// Round 12
// 138.111 us; speedup vs baseline: 1.3206x; 1.0123x over previous
//
#include <hip/hip_runtime.h>
#include <hip/hip_bf16.h>
#include <cstdint>
#include <cstddef>

// Problem constants
#define Hh    12
#define Nseq  2048
#define PSTR  1152      // concat projection width: 192 q | 384 kv | 144 qp | 432 kvp
#define EPSm  1e-8f
#define MASKV 1024.0f   // (mi*M)*mj + (-M)*1 == 0 exactly when masks==1

typedef unsigned short ushort_t;
typedef __attribute__((ext_vector_type(8))) short bf8_t;   // 8 bf16 (4 VGPRs)
typedef __attribute__((ext_vector_type(4))) short s4_t;    // 4 bf16 (2 VGPRs)
typedef __attribute__((ext_vector_type(4))) float f4_t;    // MFMA C/D

// ws offsets (floats). Total 5,051,520 fl = 20.2 MB <= proven 29.1 MB budget.
#define OFF_PALL   0         // fp32 [2048][1152]
#define OFF_WALLB  2359296   // bf16 [1152][384]
#define OFF_BALL   2580480   // fp32 [1152]
#define OFF_SB     2581632   // bf16 [2048][384]
#define OFF_WOUTB  2974848   // bf16 [384][576]
#define OFF_FEATSB 3085440   // bf16 [2048][576]
#define OFF_AU     3675264   // bf16 [12][2048][32]
#define OFF_KU     4068480   // bf16 [12][2048][32]
#define OFF_VU     4461696   // bf16 [12][64][48][32]  tile-blocked (r11-verified)
#define WS_FLOATS  5051520

__device__ __forceinline__ ushort_t bfr(float x) {   // fp32 -> bf16 bits, RNE
    union { float f; uint32_t u; } v; v.f = x;
    uint32_t r = v.u + 0x7FFFu + ((v.u >> 16) & 1u);
    return (ushort_t)(r >> 16);
}

// ---------------------------------------------------------------------------
// prep (verified r7/r8): concat weights -> bf16, biases -> fp32, s/Wout bf16.
// ---------------------------------------------------------------------------
__global__ __launch_bounds__(256) void prep(
    const float* __restrict__ s, const float* __restrict__ Wout,
    const float* __restrict__ Wq, const float* __restrict__ Wkv,
    const float* __restrict__ Wqp, const float* __restrict__ Wkvp,
    const float* __restrict__ bq, const float* __restrict__ bkv,
    const float* __restrict__ bqp, const float* __restrict__ bkvp,
    ushort_t* __restrict__ Wallb, float* __restrict__ ball,
    ushort_t* __restrict__ sb, ushort_t* __restrict__ Woutb)
{
    int idx = blockIdx.x * 256 + threadIdx.x;
    if (idx < 1152 * 384) {
        int r = idx / 384, c = idx % 384;
        float v;
        if (r < 192)      v = Wq [(size_t)r * 384 + c];
        else if (r < 576) v = Wkv[(size_t)(r - 192) * 384 + c];
        else if (r < 720) v = Wqp[(size_t)(r - 576) * 384 + c];
        else              v = Wkvp[(size_t)(r - 720) * 384 + c];
        Wallb[idx] = bfr(v);
    }
    if (idx < 1152) {
        float v;
        if (idx < 192)      v = bq[idx];
        else if (idx < 576) v = bkv[idx - 192];
        else if (idx < 720) v = bqp[idx - 576];
        else                v = bkvp[idx - 720];
        ball[idx] = v;
    }
    if (idx < 2048 * 384) sb[idx] = bfr(s[idx]);
    if (idx < 384 * 576)  Woutb[idx] = bfr(Wout[idx]);
}

// ---------------------------------------------------------------------------
// bf16 MFMA GEMM (verified r8). C[m][n] = sum_k A[m][k]*W[n][k] + bias[n].
// ---------------------------------------------------------------------------
template<int BM, int BN>
__global__ __launch_bounds__(256) void gemm_mfma(
    const ushort_t* __restrict__ A, const ushort_t* __restrict__ W,
    const float* __restrict__ bias, float* __restrict__ C,
    int M, int Nn, int K)
{
    constexpr int WM = BM / 2, WN = BN / 2;
    constexpr int MI = WM / 16, NJ = WN / 16;
    __shared__ ushort_t As[BM][40];
    __shared__ ushort_t Bs[BN][40];

    const int bm = blockIdx.y * BM;
    const int bn = blockIdx.x * BN;
    const int t  = threadIdx.x;
    const int w  = t >> 6, lane = t & 63;
    const int m  = lane & 15, quad = lane >> 4;
    const int wm = (w >> 1) * WM, wn = (w & 1) * WN;

    f4_t acc[MI][NJ];
    #pragma unroll
    for (int i2 = 0; i2 < MI; ++i2)
        #pragma unroll
        for (int j2 = 0; j2 < NJ; ++j2)
            acc[i2][j2] = (f4_t){0.f, 0.f, 0.f, 0.f};

    for (int k0 = 0; k0 < K; k0 += 32) {
        #pragma unroll
        for (int u = 0; u < BM / 64; ++u) {
            int e = t + u * 256;
            int r = e >> 2, kk = (e & 3) * 8;
            *(uint4*)&As[r][kk] = *(const uint4*)&A[(size_t)(bm + r) * K + k0 + kk];
        }
        #pragma unroll
        for (int u = 0; u < BN / 64; ++u) {
            int e = t + u * 256;
            int r = e >> 2, kk = (e & 3) * 8;
            *(uint4*)&Bs[r][kk] = *(const uint4*)&W[(size_t)(bn + r) * K + k0 + kk];
        }
        __syncthreads();
        bf8_t af[MI], bfv[NJ];
        #pragma unroll
        for (int x = 0; x < MI; ++x) af[x]  = *(const bf8_t*)&As[wm + x * 16 + m][quad * 8];
        #pragma unroll
        for (int x = 0; x < NJ; ++x) bfv[x] = *(const bf8_t*)&Bs[wn + x * 16 + m][quad * 8];
        #pragma unroll
        for (int i2 = 0; i2 < MI; ++i2)
            #pragma unroll
            for (int j2 = 0; j2 < NJ; ++j2)
                acc[i2][j2] = __builtin_amdgcn_mfma_f32_16x16x32_bf16(
                    af[i2], bfv[j2], acc[i2][j2], 0, 0, 0);
        __syncthreads();
    }

    #pragma unroll
    for (int j2 = 0; j2 < NJ; ++j2) {
        int col = bn + wn + j2 * 16 + m;
        float bb = bias[col];
        #pragma unroll
        for (int i2 = 0; i2 < MI; ++i2)
            #pragma unroll
            for (int r = 0; r < 4; ++r) {
                int row = bm + wm + i2 * 16 + quad * 4 + r;
                C[(size_t)row * Nn + col] = acc[i2][j2][r] + bb;
            }
    }
}

// ---------------------------------------------------------------------------
// pack_aug (verified r11): LDS-staged reads; VU tile-blocked [h][j>>5][c][j&31].
// ---------------------------------------------------------------------------
__global__ __launch_bounds__(128) void pack_aug(
    const float* __restrict__ Pall, const float* __restrict__ rot,
    const float* __restrict__ trans, const float* __restrict__ mask,
    const float* __restrict__ hwv,
    ushort_t* __restrict__ AU, ushort_t* __restrict__ KU,
    ushort_t* __restrict__ VU)
{
    __shared__ float S[8][1156];
    const int n0 = blockIdx.x * 8;
    const int t  = threadIdx.x;

    #pragma unroll
    for (int u = 0; u < 18; ++u) {
        int f = t + u * 128;
        int rr = f / 288, c4 = f % 288;
        float4 v = *(const float4*)&Pall[(size_t)(n0 + rr) * PSTR + c4 * 4];
        *(float4*)&S[rr][c4 * 4] = v;
    }
    __syncthreads();

    if (t >= 96) return;
    const int nl = t & 7, h = t >> 3;
    const int n  = n0 + nl;
    const float* row = S[nl];

    const float whw = 0.5f * logf(1.0f + expf(hwv[h])) * 0.13608276348795434f;
    const float scale_a = 0.14433756729740643f;   // sqrt(1/48)

    float R[9], T[3];
    #pragma unroll
    for (int z = 0; z < 9; ++z) R[z] = rot[(size_t)n * 9 + z];
    #pragma unroll
    for (int d = 0; d < 3; ++d) T[d] = trans[(size_t)n * 3 + d];

    float qpv[12], q2 = 0.f;
    #pragma unroll
    for (int p = 0; p < 4; ++p) {
        float r0 = row[576 +   0 + h * 4 + p];
        float r1 = row[576 +  48 + h * 4 + p];
        float r2 = row[576 +  96 + h * 4 + p];
        #pragma unroll
        for (int d = 0; d < 3; ++d) {
            float o = R[d*3+0]*r0 + R[d*3+1]*r1 + R[d*3+2]*r2 + T[d];
            qpv[p * 3 + d] = o;
            q2 += o * o;
        }
    }

    float kpv[12], vpv[24], k2 = 0.f;
    #pragma unroll
    for (int pt = 0; pt < 12; ++pt) {
        float r0 = row[720 +   0 + h * 12 + pt];
        float r1 = row[720 + 144 + h * 12 + pt];
        float r2 = row[720 + 288 + h * 12 + pt];
        #pragma unroll
        for (int d = 0; d < 3; ++d) {
            float o = R[d*3+0]*r0 + R[d*3+1]*r1 + R[d*3+2]*r2 + T[d];
            if (pt < 4) { kpv[pt * 3 + d] = o; k2 += o * o; }
            else        { vpv[(pt - 4) * 3 + d] = o; }
        }
    }

    const float mi = mask[n];

    __align__(16) ushort_t a32[32];
    #pragma unroll
    for (int c = 0; c < 16; ++c) a32[c] = bfr(row[h * 16 + c] * scale_a);
    #pragma unroll
    for (int z = 0; z < 12; ++z) a32[16 + z] = bfr(qpv[z] * (2.0f * whw));
    a32[28] = bfr(-whw);
    a32[29] = bfr(-whw * q2);
    a32[30] = bfr(mi * MASKV);
    a32[31] = bfr(-MASKV);
    ushort_t* adst = AU + ((size_t)h * Nseq + n) * 32;
    #pragma unroll
    for (int u = 0; u < 4; ++u) ((uint4*)adst)[u] = ((const uint4*)a32)[u];

    const float* kvrow = row + 192 + h * 32;
    __align__(16) ushort_t k32[32];
    #pragma unroll
    for (int c = 0; c < 16; ++c) k32[c] = bfr(kvrow[c]);
    #pragma unroll
    for (int z = 0; z < 12; ++z) k32[16 + z] = bfr(kpv[z]);
    k32[28] = bfr(k2);
    k32[29] = 0x3F80;
    k32[30] = bfr(mi);
    k32[31] = 0x3F80;
    ushort_t* kdst = KU + ((size_t)h * Nseq + n) * 32;
    #pragma unroll
    for (int u = 0; u < 4; ++u) ((uint4*)kdst)[u] = ((const uint4*)k32)[u];

    // tile-blocked V: (h, j=n, c) at h*98304 + (n>>5)*1536 + c*32 + (n&31)
    ushort_t* vb = VU + (size_t)h * 98304 + (size_t)(n >> 5) * 1536 + (n & 31);
    #pragma unroll
    for (int c = 0; c < 16; ++c) vb[c * 32] = bfr(kvrow[16 + c]);
    #pragma unroll
    for (int z = 0; z < 24; ++z) vb[(16 + z) * 32] = bfr(vpv[z]);
    vb[40 * 32] = 0x3F80;
    #pragma unroll
    for (int c = 41; c < 48; ++c) vb[c * 32] = 0;
}

__device__ __forceinline__ bf8_t expack(f4_t s) {   // exp -> bf16 low4, zero high
    s4_t p;
    p[0] = (short)bfr(__expf(s[0]));
    p[1] = (short)bfr(__expf(s[1]));
    p[2] = (short)bfr(__expf(s[2]));
    p[3] = (short)bfr(__expf(s[3]));
    s4_t z = (s4_t)0;
    return __builtin_shufflevector(p, z, 0, 1, 2, 3, 4, 5, 6, 7);
}

__device__ __forceinline__ bf8_t vpad(s4_t v) {     // V low4, zero high
    s4_t z = (s4_t)0;
    return __builtin_shufflevector(v, z, 0, 1, 2, 3, 4, 5, 6, 7);
}

struct KVTile { bf8_t kb0, kb1; s4_t v[6]; };

__device__ __forceinline__ KVTile load_tile(
    const ushort_t* __restrict__ kb_base, const ushort_t* __restrict__ vt,
    int m, int quad)
{
    KVTile tl;
    tl.kb0  = *(const bf8_t*)(kb_base);
    tl.kb1  = *(const bf8_t*)(kb_base + 16 * 32);
    tl.v[0] = *(const s4_t*)(vt +        m * 32 +      quad * 4);
    tl.v[1] = *(const s4_t*)(vt +  512 + m * 32 +      quad * 4);
    tl.v[2] = *(const s4_t*)(vt + 1024 + m * 32 +      quad * 4);
    tl.v[3] = *(const s4_t*)(vt +        m * 32 + 16 + quad * 4);
    tl.v[4] = *(const s4_t*)(vt +  512 + m * 32 + 16 + quad * 4);
    tl.v[5] = *(const s4_t*)(vt + 1024 + m * 32 + 16 + quad * 4);
    return tl;
}

// ---------------------------------------------------------------------------
// MFMA attention (r11-verified math) + PHASE-ROTATED j-tile order: block b
// starts its 16-tile sweep at phase (b*5)&15, decorrelating the 64 blocks
// per head that previously read identical K/V addresses in lockstep (L2
// same-line contention). Partials are plain sums -> order-independent.
// ---------------------------------------------------------------------------
__global__ __launch_bounds__(256, 3) void attn_mfma(
    const ushort_t* __restrict__ AU, const ushort_t* __restrict__ KU,
    const ushort_t* __restrict__ VU,
    const float* __restrict__ rot, const float* __restrict__ trans,
    ushort_t* __restrict__ featsb)
{
    __shared__ float red[4][32][49];   // 25088 B

    const int b    = blockIdx.x;
    const int h    = b >> 6;
    const int ib   = b & 63;
    const int t    = threadIdx.x;
    const int w    = t >> 6;
    const int lane = t & 63;
    const int m    = lane & 15;
    const int quad = lane >> 4;
    const int i0   = ib * 32;
    const int phase = (b * 5) & 15;

    bf8_t afA = *(const bf8_t*)(AU + ((size_t)h * Nseq + i0 +      m) * 32 + quad * 8);
    bf8_t afB = *(const bf8_t*)(AU + ((size_t)h * Nseq + i0 + 16 + m) * 32 + quad * 8);

    f4_t acc[6];
    #pragma unroll
    for (int z = 0; z < 6; ++z) acc[z] = (f4_t){0.f, 0.f, 0.f, 0.f};

    const int jb0 = w * 512;
    const ushort_t* kb_base = KU + ((size_t)h * Nseq + jb0 + m) * 32 + quad * 8;
    const ushort_t* v_base  = VU + (size_t)h * 98304 + (size_t)jb0 * 48;

    KVTile cur = load_tile(kb_base + (size_t)phase * 1024,
                           v_base + (size_t)phase * 1536, m, quad);

    #pragma unroll
    for (int jt = 0; jt < 16; ++jt) {
        f4_t zz = (f4_t){0.f, 0.f, 0.f, 0.f};
        f4_t sXA = __builtin_amdgcn_mfma_f32_16x16x32_bf16(cur.kb0, afA, zz, 0, 0, 0);
        f4_t sXB = __builtin_amdgcn_mfma_f32_16x16x32_bf16(cur.kb0, afB, zz, 0, 0, 0);
        f4_t sYA = __builtin_amdgcn_mfma_f32_16x16x32_bf16(cur.kb1, afA, zz, 0, 0, 0);
        f4_t sYB = __builtin_amdgcn_mfma_f32_16x16x32_bf16(cur.kb1, afB, zz, 0, 0, 0);

        KVTile nxt;
        if (jt < 15) {
            int jx = (jt + 1 + phase) & 15;
            nxt = load_tile(kb_base + (size_t)jx * 1024,
                            v_base + (size_t)jx * 1536, m, quad);
        }

        bf8_t pXA = expack(sXA), pXB = expack(sXB);
        bf8_t pYA = expack(sYA), pYB = expack(sYB);
        bf8_t f0 = vpad(cur.v[0]), f1 = vpad(cur.v[1]), f2 = vpad(cur.v[2]);
        bf8_t g0 = vpad(cur.v[3]), g1 = vpad(cur.v[4]), g2 = vpad(cur.v[5]);

        acc[0] = __builtin_amdgcn_mfma_f32_16x16x32_bf16(pXA, f0, acc[0], 0, 0, 0);
        acc[0] = __builtin_amdgcn_mfma_f32_16x16x32_bf16(pYA, g0, acc[0], 0, 0, 0);
        acc[1] = __builtin_amdgcn_mfma_f32_16x16x32_bf16(pXA, f1, acc[1], 0, 0, 0);
        acc[1] = __builtin_amdgcn_mfma_f32_16x16x32_bf16(pYA, g1, acc[1], 0, 0, 0);
        acc[2] = __builtin_amdgcn_mfma_f32_16x16x32_bf16(pXA, f2, acc[2], 0, 0, 0);
        acc[2] = __builtin_amdgcn_mfma_f32_16x16x32_bf16(pYA, g2, acc[2], 0, 0, 0);
        acc[3] = __builtin_amdgcn_mfma_f32_16x16x32_bf16(pXB, f0, acc[3], 0, 0, 0);
        acc[3] = __builtin_amdgcn_mfma_f32_16x16x32_bf16(pYB, g0, acc[3], 0, 0, 0);
        acc[4] = __builtin_amdgcn_mfma_f32_16x16x32_bf16(pXB, f1, acc[4], 0, 0, 0);
        acc[4] = __builtin_amdgcn_mfma_f32_16x16x32_bf16(pYB, g1, acc[4], 0, 0, 0);
        acc[5] = __builtin_amdgcn_mfma_f32_16x16x32_bf16(pXB, f2, acc[5], 0, 0, 0);
        acc[5] = __builtin_amdgcn_mfma_f32_16x16x32_bf16(pYB, g2, acc[5], 0, 0, 0);

        cur = nxt;
    }

    #pragma unroll
    for (int r = 0; r < 4; ++r) {
        red[w][quad * 4 + r][m]           = acc[0][r];
        red[w][quad * 4 + r][16 + m]      = acc[1][r];
        red[w][quad * 4 + r][32 + m]      = acc[2][r];
        red[w][16 + quad * 4 + r][m]      = acc[3][r];
        red[w][16 + quad * 4 + r][16 + m] = acc[4][r];
        red[w][16 + quad * 4 + r][32 + m] = acc[5][r];
    }
    __syncthreads();

    #pragma unroll
    for (int u = 0; u < 6; ++u) {
        int e = t + u * 256;
        int rr = e / 48, cc = e % 48;
        red[0][rr][cc] = red[0][rr][cc] + red[1][rr][cc] + red[2][rr][cc] + red[3][rr][cc];
    }
    __syncthreads();

    if (t < 32) {
        const int i = i0 + t;
        float L   = red[0][t][40];
        float inv = 1.0f / L;
        float o[40];
        #pragma unroll
        for (int z = 0; z < 40; ++z) o[z] = red[0][t][z] * inv;

        ushort_t* f = featsb + (size_t)i * 576;
        #pragma unroll
        for (int c = 0; c < 16; ++c) f[h * 16 + c] = bfr(o[c]);

        float R[9], T[3];
        #pragma unroll
        for (int z = 0; z < 9; ++z) R[z] = rot[(size_t)i * 9 + z];
        #pragma unroll
        for (int d = 0; d < 3; ++d) T[d] = trans[(size_t)i * 3 + d];

        #pragma unroll
        for (int p8 = 0; p8 < 8; ++p8) {
            float g0 = o[16 + p8 * 3 + 0] - T[0];
            float g1 = o[16 + p8 * 3 + 1] - T[1];
            float g2 = o[16 + p8 * 3 + 2] - T[2];
            float xx = R[0] * g0 + R[3] * g1 + R[6] * g2;
            float yy = R[1] * g0 + R[4] * g1 + R[7] * g2;
            float zz = R[2] * g0 + R[5] * g1 + R[8] * g2;
            float dist = sqrtf(xx * xx + yy * yy + zz * zz + EPSm);
            f[192 + h * 8 + p8] = bfr(xx);
            f[288 + h * 8 + p8] = bfr(yy);
            f[384 + h * 8 + p8] = bfr(zz);
            f[480 + h * 8 + p8] = bfr(dist);
        }
    }
}

// ---------------------------------------------------------------------------
extern "C" void kernel_launch(void* const* d_in, const int* in_sizes, int n_in,
                              void* d_out, int out_size, void* d_ws, size_t ws_size,
                              hipStream_t stream)
{
    const float* s     = (const float*)d_in[0];
    const float* rot   = (const float*)d_in[1];
    const float* trans = (const float*)d_in[2];
    const float* mask  = (const float*)d_in[3];
    const float* Wq    = (const float*)d_in[4];
    const float* bq    = (const float*)d_in[5];
    const float* Wkv   = (const float*)d_in[6];
    const float* bkv   = (const float*)d_in[7];
    const float* Wqp   = (const float*)d_in[8];
    const float* bqp   = (const float*)d_in[9];
    const float* Wkvp  = (const float*)d_in[10];
    const float* bkvp  = (const float*)d_in[11];
    const float* hwv   = (const float*)d_in[12];
    const float* Wout  = (const float*)d_in[13];
    const float* bout  = (const float*)d_in[14];
    float* out = (float*)d_out;
    float* ws  = (float*)d_ws;

    if (ws_size < (size_t)WS_FLOATS * sizeof(float)) return;

    float*    Pall   = ws + OFF_PALL;
    ushort_t* Wallb  = (ushort_t*)(ws + OFF_WALLB);
    float*    ball   = ws + OFF_BALL;
    ushort_t* sb     = (ushort_t*)(ws + OFF_SB);
    ushort_t* Woutb  = (ushort_t*)(ws + OFF_WOUTB);
    ushort_t* featsb = (ushort_t*)(ws + OFF_FEATSB);
    ushort_t* AU     = (ushort_t*)(ws + OFF_AU);
    ushort_t* KU     = (ushort_t*)(ws + OFF_KU);
    ushort_t* VU     = (ushort_t*)(ws + OFF_VU);

    prep<<<dim3(3072), 256, 0, stream>>>(s, Wout, Wq, Wkv, Wqp, Wkvp,
                                         bq, bkv, bqp, bkvp,
                                         Wallb, ball, sb, Woutb);

    // 64x64 tile: 576 blocks = 2.25/CU (was 288 = 1.125/CU, tail imbalance)
    gemm_mfma<64, 64><<<dim3(1152 / 64, 2048 / 64), 256, 0, stream>>>(
        sb, Wallb, ball, Pall, 2048, 1152, 384);

    pack_aug<<<dim3(256), 128, 0, stream>>>(Pall, rot, trans, mask, hwv,
                                            AU, KU, VU);

    attn_mfma<<<dim3(768), 256, 0, stream>>>(AU, KU, VU, rot, trans, featsb);

    gemm_mfma<64, 64><<<dim3(384 / 64, 2048 / 64), 256, 0, stream>>>(
        featsb, Woutb, bout, out, 2048, 384, 576);
}

// Round 14
// 137.982 us; speedup vs baseline: 1.3218x; 1.0009x over previous
//
#include <hip/hip_runtime.h>
#include <hip/hip_bf16.h>
#include <cstdint>
#include <cstddef>

// Problem constants
#define Hh    12
#define Nseq  2048
#define PSTR  1152      // concat projection width: 192 q | 384 kv | 144 qp | 432 kvp
#define EPSm  1e-8f
#define MASKV 1024.0f   // (mi*M)*mj + (-M)*1 == 0 exactly when masks==1

typedef unsigned short ushort_t;
typedef __attribute__((ext_vector_type(8))) short bf8_t;   // 8 bf16 (4 VGPRs)
typedef __attribute__((ext_vector_type(4))) short s4_t;    // 4 bf16 (2 VGPRs)
typedef __attribute__((ext_vector_type(4))) float f4_t;    // MFMA C/D

// ws offsets (floats). Total 7,066,752 fl = 28.3 MB <= proven 29.1 MB budget.
#define OFF_PALL   0         // fp32 [2048][1152]
#define OFF_WALLB  2359296   // bf16 [1152][384]
#define OFF_BALL   2580480   // fp32 [1152]
#define OFF_SB     2581632   // bf16 [2048][384]
#define OFF_WOUTB  2974848   // bf16 [384][576]
#define OFF_FEATSB 3085440   // bf16 [2048][576]
#define OFF_AU     3675264   // bf16 [12][2048][32]
#define OFF_KU     4068480   // bf16 [12][2048][32]
#define OFF_VU     4461696   // bf16 [12][64][48][32]  tile-blocked (r11-verified)
#define OFF_P0     5051520   // fp32 [12][2048][41]  j-half-0 partials
#define OFF_P1     6059136   // fp32 [12][2048][41]  j-half-1 partials
#define WS_FLOATS  7066752

__device__ __forceinline__ ushort_t bfr(float x) {   // fp32 -> bf16 bits, RNE
    union { float f; uint32_t u; } v; v.f = x;
    uint32_t r = v.u + 0x7FFFu + ((v.u >> 16) & 1u);
    return (ushort_t)(r >> 16);
}

// ---------------------------------------------------------------------------
// prep (verified r7/r8): concat weights -> bf16, biases -> fp32, s/Wout bf16.
// ---------------------------------------------------------------------------
__global__ __launch_bounds__(256) void prep(
    const float* __restrict__ s, const float* __restrict__ Wout,
    const float* __restrict__ Wq, const float* __restrict__ Wkv,
    const float* __restrict__ Wqp, const float* __restrict__ Wkvp,
    const float* __restrict__ bq, const float* __restrict__ bkv,
    const float* __restrict__ bqp, const float* __restrict__ bkvp,
    ushort_t* __restrict__ Wallb, float* __restrict__ ball,
    ushort_t* __restrict__ sb, ushort_t* __restrict__ Woutb)
{
    int idx = blockIdx.x * 256 + threadIdx.x;
    if (idx < 1152 * 384) {
        int r = idx / 384, c = idx % 384;
        float v;
        if (r < 192)      v = Wq [(size_t)r * 384 + c];
        else if (r < 576) v = Wkv[(size_t)(r - 192) * 384 + c];
        else if (r < 720) v = Wqp[(size_t)(r - 576) * 384 + c];
        else              v = Wkvp[(size_t)(r - 720) * 384 + c];
        Wallb[idx] = bfr(v);
    }
    if (idx < 1152) {
        float v;
        if (idx < 192)      v = bq[idx];
        else if (idx < 576) v = bkv[idx - 192];
        else if (idx < 720) v = bqp[idx - 576];
        else                v = bkvp[idx - 720];
        ball[idx] = v;
    }
    if (idx < 2048 * 384) sb[idx] = bfr(s[idx]);
    if (idx < 384 * 576)  Woutb[idx] = bfr(Wout[idx]);
}

// ---------------------------------------------------------------------------
// bf16 MFMA GEMM (verified r8). C[m][n] = sum_k A[m][k]*W[n][k] + bias[n].
// ---------------------------------------------------------------------------
template<int BM, int BN>
__global__ __launch_bounds__(256) void gemm_mfma(
    const ushort_t* __restrict__ A, const ushort_t* __restrict__ W,
    const float* __restrict__ bias, float* __restrict__ C,
    int M, int Nn, int K)
{
    constexpr int WM = BM / 2, WN = BN / 2;
    constexpr int MI = WM / 16, NJ = WN / 16;
    __shared__ ushort_t As[BM][40];
    __shared__ ushort_t Bs[BN][40];

    const int bm = blockIdx.y * BM;
    const int bn = blockIdx.x * BN;
    const int t  = threadIdx.x;
    const int w  = t >> 6, lane = t & 63;
    const int m  = lane & 15, quad = lane >> 4;
    const int wm = (w >> 1) * WM, wn = (w & 1) * WN;

    f4_t acc[MI][NJ];
    #pragma unroll
    for (int i2 = 0; i2 < MI; ++i2)
        #pragma unroll
        for (int j2 = 0; j2 < NJ; ++j2)
            acc[i2][j2] = (f4_t){0.f, 0.f, 0.f, 0.f};

    for (int k0 = 0; k0 < K; k0 += 32) {
        #pragma unroll
        for (int u = 0; u < BM / 64; ++u) {
            int e = t + u * 256;
            int r = e >> 2, kk = (e & 3) * 8;
            *(uint4*)&As[r][kk] = *(const uint4*)&A[(size_t)(bm + r) * K + k0 + kk];
        }
        #pragma unroll
        for (int u = 0; u < BN / 64; ++u) {
            int e = t + u * 256;
            int r = e >> 2, kk = (e & 3) * 8;
            *(uint4*)&Bs[r][kk] = *(const uint4*)&W[(size_t)(bn + r) * K + k0 + kk];
        }
        __syncthreads();
        bf8_t af[MI], bfv[NJ];
        #pragma unroll
        for (int x = 0; x < MI; ++x) af[x]  = *(const bf8_t*)&As[wm + x * 16 + m][quad * 8];
        #pragma unroll
        for (int x = 0; x < NJ; ++x) bfv[x] = *(const bf8_t*)&Bs[wn + x * 16 + m][quad * 8];
        #pragma unroll
        for (int i2 = 0; i2 < MI; ++i2)
            #pragma unroll
            for (int j2 = 0; j2 < NJ; ++j2)
                acc[i2][j2] = __builtin_amdgcn_mfma_f32_16x16x32_bf16(
                    af[i2], bfv[j2], acc[i2][j2], 0, 0, 0);
        __syncthreads();
    }

    #pragma unroll
    for (int j2 = 0; j2 < NJ; ++j2) {
        int col = bn + wn + j2 * 16 + m;
        float bb = bias[col];
        #pragma unroll
        for (int i2 = 0; i2 < MI; ++i2)
            #pragma unroll
            for (int r = 0; r < 4; ++r) {
                int row = bm + wm + i2 * 16 + quad * 4 + r;
                C[(size_t)row * Nn + col] = acc[i2][j2][r] + bb;
            }
    }
}

// ---------------------------------------------------------------------------
// pack_aug (verified r11): LDS-staged reads; VU tile-blocked [h][j>>5][c][j&31].
// ---------------------------------------------------------------------------
__global__ __launch_bounds__(128) void pack_aug(
    const float* __restrict__ Pall, const float* __restrict__ rot,
    const float* __restrict__ trans, const float* __restrict__ mask,
    const float* __restrict__ hwv,
    ushort_t* __restrict__ AU, ushort_t* __restrict__ KU,
    ushort_t* __restrict__ VU)
{
    __shared__ float S[8][1156];
    const int n0 = blockIdx.x * 8;
    const int t  = threadIdx.x;

    #pragma unroll
    for (int u = 0; u < 18; ++u) {
        int f = t + u * 128;
        int rr = f / 288, c4 = f % 288;
        float4 v = *(const float4*)&Pall[(size_t)(n0 + rr) * PSTR + c4 * 4];
        *(float4*)&S[rr][c4 * 4] = v;
    }
    __syncthreads();

    if (t >= 96) return;
    const int nl = t & 7, h = t >> 3;
    const int n  = n0 + nl;
    const float* row = S[nl];

    const float whw = 0.5f * logf(1.0f + expf(hwv[h])) * 0.13608276348795434f;
    const float scale_a = 0.14433756729740643f;   // sqrt(1/48)

    float R[9], T[3];
    #pragma unroll
    for (int z = 0; z < 9; ++z) R[z] = rot[(size_t)n * 9 + z];
    #pragma unroll
    for (int d = 0; d < 3; ++d) T[d] = trans[(size_t)n * 3 + d];

    float qpv[12], q2 = 0.f;
    #pragma unroll
    for (int p = 0; p < 4; ++p) {
        float r0 = row[576 +   0 + h * 4 + p];
        float r1 = row[576 +  48 + h * 4 + p];
        float r2 = row[576 +  96 + h * 4 + p];
        #pragma unroll
        for (int d = 0; d < 3; ++d) {
            float o = R[d*3+0]*r0 + R[d*3+1]*r1 + R[d*3+2]*r2 + T[d];
            qpv[p * 3 + d] = o;
            q2 += o * o;
        }
    }

    float kpv[12], vpv[24], k2 = 0.f;
    #pragma unroll
    for (int pt = 0; pt < 12; ++pt) {
        float r0 = row[720 +   0 + h * 12 + pt];
        float r1 = row[720 + 144 + h * 12 + pt];
        float r2 = row[720 + 288 + h * 12 + pt];
        #pragma unroll
        for (int d = 0; d < 3; ++d) {
            float o = R[d*3+0]*r0 + R[d*3+1]*r1 + R[d*3+2]*r2 + T[d];
            if (pt < 4) { kpv[pt * 3 + d] = o; k2 += o * o; }
            else        { vpv[(pt - 4) * 3 + d] = o; }
        }
    }

    const float mi = mask[n];

    __align__(16) ushort_t a32[32];
    #pragma unroll
    for (int c = 0; c < 16; ++c) a32[c] = bfr(row[h * 16 + c] * scale_a);
    #pragma unroll
    for (int z = 0; z < 12; ++z) a32[16 + z] = bfr(qpv[z] * (2.0f * whw));
    a32[28] = bfr(-whw);
    a32[29] = bfr(-whw * q2);
    a32[30] = bfr(mi * MASKV);
    a32[31] = bfr(-MASKV);
    ushort_t* adst = AU + ((size_t)h * Nseq + n) * 32;
    #pragma unroll
    for (int u = 0; u < 4; ++u) ((uint4*)adst)[u] = ((const uint4*)a32)[u];

    const float* kvrow = row + 192 + h * 32;
    __align__(16) ushort_t k32[32];
    #pragma unroll
    for (int c = 0; c < 16; ++c) k32[c] = bfr(kvrow[c]);
    #pragma unroll
    for (int z = 0; z < 12; ++z) k32[16 + z] = bfr(kpv[z]);
    k32[28] = bfr(k2);
    k32[29] = 0x3F80;
    k32[30] = bfr(mi);
    k32[31] = 0x3F80;
    ushort_t* kdst = KU + ((size_t)h * Nseq + n) * 32;
    #pragma unroll
    for (int u = 0; u < 4; ++u) ((uint4*)kdst)[u] = ((const uint4*)k32)[u];

    // tile-blocked V: (h, j=n, c) at h*98304 + (n>>5)*1536 + c*32 + (n&31)
    ushort_t* vb = VU + (size_t)h * 98304 + (size_t)(n >> 5) * 1536 + (n & 31);
    #pragma unroll
    for (int c = 0; c < 16; ++c) vb[c * 32] = bfr(kvrow[16 + c]);
    #pragma unroll
    for (int z = 0; z < 24; ++z) vb[(16 + z) * 32] = bfr(vpv[z]);
    vb[40 * 32] = 0x3F80;
    #pragma unroll
    for (int c = 41; c < 48; ++c) vb[c * 32] = 0;
}

__device__ __forceinline__ bf8_t expack(f4_t s) {   // exp -> bf16 low4, zero high
    s4_t p;
    p[0] = (short)bfr(__expf(s[0]));
    p[1] = (short)bfr(__expf(s[1]));
    p[2] = (short)bfr(__expf(s[2]));
    p[3] = (short)bfr(__expf(s[3]));
    s4_t z = (s4_t)0;
    return __builtin_shufflevector(p, z, 0, 1, 2, 3, 4, 5, 6, 7);
}

__device__ __forceinline__ bf8_t vpad(s4_t v) {     // V low4, zero high
    s4_t z = (s4_t)0;
    return __builtin_shufflevector(v, z, 0, 1, 2, 3, 4, 5, 6, 7);
}

struct KVTile { bf8_t kb0, kb1; s4_t v[6]; };

__device__ __forceinline__ KVTile load_tile(
    const ushort_t* __restrict__ kb_base, const ushort_t* __restrict__ vt,
    int m, int quad)
{
    KVTile tl;
    tl.kb0  = *(const bf8_t*)(kb_base);
    tl.kb1  = *(const bf8_t*)(kb_base + 16 * 32);
    tl.v[0] = *(const s4_t*)(vt +        m * 32 +      quad * 4);
    tl.v[1] = *(const s4_t*)(vt +  512 + m * 32 +      quad * 4);
    tl.v[2] = *(const s4_t*)(vt + 1024 + m * 32 +      quad * 4);
    tl.v[3] = *(const s4_t*)(vt +        m * 32 + 16 + quad * 4);
    tl.v[4] = *(const s4_t*)(vt +  512 + m * 32 + 16 + quad * 4);
    tl.v[5] = *(const s4_t*)(vt + 1024 + m * 32 + 16 + quad * 4);
    return tl;
}

// ---------------------------------------------------------------------------
// MFMA attention v5b: i-tile 64 (4 A-frags), j-half 1024 per block (2x
// intensity vs r12), grid 768 = 12h x 32ib x 2jh, 3 blocks/CU. *** r13 BUG
// FIXED: blocks covering half of j write UNNORMALIZED partials (+L) to
// part0/part1; normalization happens in attn_fin after both halves exist. ***
// ---------------------------------------------------------------------------
__global__ __launch_bounds__(256, 3) void attn_mfma(
    const ushort_t* __restrict__ AU, const ushort_t* __restrict__ KU,
    const ushort_t* __restrict__ VU,
    float* __restrict__ part0, float* __restrict__ part1)
{
    __shared__ float red[4][64][49];   // 50176 B -> 3 blocks/CU

    const int b    = blockIdx.x;
    const int h    = b >> 6;           // 0..11
    const int r6   = b & 63;
    const int ib   = r6 >> 1;          // 0..31
    const int jh   = r6 & 1;           // 0..1
    const int t    = threadIdx.x;
    const int w    = t >> 6;
    const int lane = t & 63;
    const int m    = lane & 15;
    const int quad = lane >> 4;
    const int i0   = ib * 64;

    bf8_t af[4];
    #pragma unroll
    for (int x = 0; x < 4; ++x)
        af[x] = *(const bf8_t*)(AU + ((size_t)h * Nseq + i0 + x * 16 + m) * 32 + quad * 8);

    f4_t acc[12];   // [x*3 + vblk]
    #pragma unroll
    for (int z = 0; z < 12; ++z) acc[z] = (f4_t){0.f, 0.f, 0.f, 0.f};

    const int jbeg = jh * 1024 + w * 256;
    const ushort_t* kb_base = KU + ((size_t)h * Nseq + jbeg + m) * 32 + quad * 8;
    const ushort_t* v_base  = VU + (size_t)h * 98304 + (size_t)jbeg * 48;

    KVTile cur = load_tile(kb_base, v_base, m, quad);

    #pragma unroll
    for (int jt = 0; jt < 8; ++jt) {
        KVTile nxt;
        if (jt < 7)
            nxt = load_tile(kb_base + (size_t)(jt + 1) * 1024,
                            v_base + (size_t)(jt + 1) * 1536, m, quad);

        bf8_t f0 = vpad(cur.v[0]), f1 = vpad(cur.v[1]), f2 = vpad(cur.v[2]);
        bf8_t g0 = vpad(cur.v[3]), g1 = vpad(cur.v[4]), g2 = vpad(cur.v[5]);
        f4_t zz = (f4_t){0.f, 0.f, 0.f, 0.f};

        #pragma unroll
        for (int x = 0; x < 4; ++x) {
            f4_t sX = __builtin_amdgcn_mfma_f32_16x16x32_bf16(cur.kb0, af[x], zz, 0, 0, 0);
            f4_t sY = __builtin_amdgcn_mfma_f32_16x16x32_bf16(cur.kb1, af[x], zz, 0, 0, 0);
            bf8_t pX = expack(sX);
            bf8_t pY = expack(sY);
            acc[x*3+0] = __builtin_amdgcn_mfma_f32_16x16x32_bf16(pX, f0, acc[x*3+0], 0, 0, 0);
            acc[x*3+0] = __builtin_amdgcn_mfma_f32_16x16x32_bf16(pY, g0, acc[x*3+0], 0, 0, 0);
            acc[x*3+1] = __builtin_amdgcn_mfma_f32_16x16x32_bf16(pX, f1, acc[x*3+1], 0, 0, 0);
            acc[x*3+1] = __builtin_amdgcn_mfma_f32_16x16x32_bf16(pY, g1, acc[x*3+1], 0, 0, 0);
            acc[x*3+2] = __builtin_amdgcn_mfma_f32_16x16x32_bf16(pX, f2, acc[x*3+2], 0, 0, 0);
            acc[x*3+2] = __builtin_amdgcn_mfma_f32_16x16x32_bf16(pY, g2, acc[x*3+2], 0, 0, 0);
        }
        cur = nxt;
    }

    // dump per-wave partials (C/D: row=quad*4+r within 16-row subtile, col=m)
    #pragma unroll
    for (int x = 0; x < 4; ++x)
        #pragma unroll
        for (int r = 0; r < 4; ++r) {
            red[w][x * 16 + quad * 4 + r][m]      = acc[x*3+0][r];
            red[w][x * 16 + quad * 4 + r][16 + m] = acc[x*3+1][r];
            red[w][x * 16 + quad * 4 + r][32 + m] = acc[x*3+2][r];
        }
    __syncthreads();

    // sum the 4 waves: 64*48 = 3072 entries, 12 per thread
    #pragma unroll
    for (int u = 0; u < 12; ++u) {
        int e = t + u * 256;
        int rr = e / 48, cc = e % 48;
        red[0][rr][cc] = red[0][rr][cc] + red[1][rr][cc] + red[2][rr][cc] + red[3][rr][cc];
    }
    __syncthreads();

    // write UNNORMALIZED partials: 64 rows x 41 (o40 | L@40) = 2624 entries
    float* dst = (jh ? part1 : part0) + ((size_t)h * Nseq + i0) * 41;
    #pragma unroll
    for (int u = 0; u < 11; ++u) {
        int e = t + u * 256;
        if (e < 2624) {
            int rr = e / 41, cc = e % 41;
            dst[(size_t)rr * 41 + cc] = red[0][rr][cc];
        }
    }
}

// ---------------------------------------------------------------------------
// attn_fin (r5-verified structure): merge the 2 j-half partials (plain sums),
// normalize, inverse-rotate o_pt, dists -> bf16 feats.
// ---------------------------------------------------------------------------
__global__ __launch_bounds__(256) void attn_fin(
    const float* __restrict__ part0, const float* __restrict__ part1,
    const float* __restrict__ rot, const float* __restrict__ trans,
    ushort_t* __restrict__ featsb)
{
    int idx = blockIdx.x * 256 + threadIdx.x;   // i*12 + h
    if (idx >= Nseq * Hh) return;
    int i = idx / Hh, h = idx % Hh;

    const float* a = part0 + ((size_t)h * Nseq + i) * 41;
    const float* bb = part1 + ((size_t)h * Nseq + i) * 41;

    float L = a[40] + bb[40];
    float inv = 1.0f / L;
    float o[40];
    #pragma unroll
    for (int z = 0; z < 40; ++z) o[z] = (a[z] + bb[z]) * inv;

    ushort_t* f = featsb + (size_t)i * 576;
    #pragma unroll
    for (int c = 0; c < 16; ++c) f[h * 16 + c] = bfr(o[c]);

    float R[9], T[3];
    #pragma unroll
    for (int z = 0; z < 9; ++z) R[z] = rot[(size_t)i * 9 + z];
    #pragma unroll
    for (int d = 0; d < 3; ++d) T[d] = trans[(size_t)i * 3 + d];

    #pragma unroll
    for (int p8 = 0; p8 < 8; ++p8) {
        float g0 = o[16 + p8 * 3 + 0] - T[0];
        float g1 = o[16 + p8 * 3 + 1] - T[1];
        float g2 = o[16 + p8 * 3 + 2] - T[2];
        float xx = R[0] * g0 + R[3] * g1 + R[6] * g2;
        float yy = R[1] * g0 + R[4] * g1 + R[7] * g2;
        float zz = R[2] * g0 + R[5] * g1 + R[8] * g2;
        float dist = sqrtf(xx * xx + yy * yy + zz * zz + EPSm);
        f[192 + h * 8 + p8] = bfr(xx);
        f[288 + h * 8 + p8] = bfr(yy);
        f[384 + h * 8 + p8] = bfr(zz);
        f[480 + h * 8 + p8] = bfr(dist);
    }
}

// ---------------------------------------------------------------------------
extern "C" void kernel_launch(void* const* d_in, const int* in_sizes, int n_in,
                              void* d_out, int out_size, void* d_ws, size_t ws_size,
                              hipStream_t stream)
{
    const float* s     = (const float*)d_in[0];
    const float* rot   = (const float*)d_in[1];
    const float* trans = (const float*)d_in[2];
    const float* mask  = (const float*)d_in[3];
    const float* Wq    = (const float*)d_in[4];
    const float* bq    = (const float*)d_in[5];
    const float* Wkv   = (const float*)d_in[6];
    const float* bkv   = (const float*)d_in[7];
    const float* Wqp   = (const float*)d_in[8];
    const float* bqp   = (const float*)d_in[9];
    const float* Wkvp  = (const float*)d_in[10];
    const float* bkvp  = (const float*)d_in[11];
    const float* hwv   = (const float*)d_in[12];
    const float* Wout  = (const float*)d_in[13];
    const float* bout  = (const float*)d_in[14];
    float* out = (float*)d_out;
    float* ws  = (float*)d_ws;

    if (ws_size < (size_t)WS_FLOATS * sizeof(float)) return;

    float*    Pall   = ws + OFF_PALL;
    ushort_t* Wallb  = (ushort_t*)(ws + OFF_WALLB);
    float*    ball   = ws + OFF_BALL;
    ushort_t* sb     = (ushort_t*)(ws + OFF_SB);
    ushort_t* Woutb  = (ushort_t*)(ws + OFF_WOUTB);
    ushort_t* featsb = (ushort_t*)(ws + OFF_FEATSB);
    ushort_t* AU     = (ushort_t*)(ws + OFF_AU);
    ushort_t* KU     = (ushort_t*)(ws + OFF_KU);
    ushort_t* VU     = (ushort_t*)(ws + OFF_VU);
    float*    part0  = ws + OFF_P0;
    float*    part1  = ws + OFF_P1;

    prep<<<dim3(3072), 256, 0, stream>>>(s, Wout, Wq, Wkv, Wqp, Wkvp,
                                         bq, bkv, bqp, bkvp,
                                         Wallb, ball, sb, Woutb);

    gemm_mfma<64, 64><<<dim3(1152 / 64, 2048 / 64), 256, 0, stream>>>(
        sb, Wallb, ball, Pall, 2048, 1152, 384);

    pack_aug<<<dim3(256), 128, 0, stream>>>(Pall, rot, trans, mask, hwv,
                                            AU, KU, VU);

    attn_mfma<<<dim3(768), 256, 0, stream>>>(AU, KU, VU, part0, part1);

    attn_fin<<<dim3(96), 256, 0, stream>>>(part0, part1, rot, trans, featsb);

    gemm_mfma<64, 64><<<dim3(384 / 64, 2048 / 64), 256, 0, stream>>>(
        featsb, Woutb, bout, out, 2048, 384, 576);
}